// Round 1
// baseline (57.014 us; speedup 1.0000x reference)
//
#include <hip/hip_runtime.h>

#define SIG_LEN 2048
#define BATCH 16
#define BLOCK 256

__global__ __launch_bounds__(BLOCK) void ParametricInterpolation_kernel(
    const float* __restrict__ x,       // [B, N]
    const float* __restrict__ params,  // [B, 5]
    float* __restrict__ out)           // [out | curve_val], each [B, N]
{
    __shared__ float xrow[SIG_LEN];

    const int blocks_per_row = SIG_LEN / BLOCK;            // 8
    const int b = blockIdx.x / blocks_per_row;
    const int i = (blockIdx.x % blocks_per_row) * BLOCK + threadIdx.x;

    // Stage this batch-row of x into LDS (coalesced, 8 loads/thread).
    const float* xb = x + b * SIG_LEN;
    for (int j = threadIdx.x; j < SIG_LEN; j += BLOCK) xrow[j] = xb[j];
    __syncthreads();

    // p = params / SCALER, fp32 divides (correctly rounded, matches np).
    const float p0 = params[b * 5 + 0] / 1e11f;
    const float p1 = params[b * 5 + 1] / 1e7f;
    const float p2 = params[b * 5 + 2] / 1e3f;
    const float p3 = params[b * 5 + 3];
    const float p4 = params[b * 5 + 4];

    // powers of i, computed exactly in double then rounded to fp32
    // (== correctly-rounded powf, which numpy uses for idx**k).
    const double id = (double)i;
    const float pw4 = (float)(id * id * id * id);
    const float pw3 = (float)(id * id * id);
    const float pw2 = (float)(i * i);   // exact in fp32 (< 2^24)
    const float pw1 = (float)i;

    // dot in ascending-k order, fp32 FMA single accumulator
    // (mimics BLAS sgemm microkernel accumulation of p @ powers).
    float cv = fmaf(p0, pw4, 0.0f);
    cv = fmaf(p1, pw3, cv);
    cv = fmaf(p2, pw2, cv);
    cv = fmaf(p3, pw1, cv);
    cv = cv + p4;

    const float ci = rintf(cv);         // round half-to-even == np.round
    const float d  = cv - ci;           // exact (Sterbenz)

    // raw_pos and its clip are exact integers in fp32.
    const float rawpos = (float)i - ci;
    const float npos   = fminf(fmaxf(rawpos, 1.0f), 2047.0f);
    const int   m      = (int)npos;     // in [1, 2047]

    // exp(-t^4) in fp32 is nonzero only for |t| <= 3 (k1: t = npos - j,
    // k2 center shifted by +1). dj in [-4, 4] covers both windows; taps
    // outside [0, N) are excluded, which also truncates the denominators
    // exactly as the reference's full-row sum does.
    float n1 = 0.0f, den1 = 0.0f, n2 = 0.0f, den2 = 0.0f;
#pragma unroll
    for (int dj = -4; dj <= 4; ++dj) {
        const int j = m + dj;
        if (j < 0 || j >= SIG_LEN) continue;
        const float t  = npos - (float)j;   // exact integer
        const float t2 = t * t;
        const float w1 = expf(-(t2 * t2));  // (t^2)^2 exact for |t|<=4
        const float u  = t - 1.0f;
        const float u2 = u * u;
        const float w2 = expf(-(u2 * u2));
        const float xv = xrow[j];
        n1   = fmaf(xv, w1, n1);
        den1 += w1;
        n2   = fmaf(xv, w2, n2);
        den2 += w2;
    }

    const float a1 = n1 / den1;
    const float a2 = n2 / den2;
    const float o  = a1 * (1.0f - d) + a2 * d;

    out[b * SIG_LEN + i] = o;
    out[BATCH * SIG_LEN + b * SIG_LEN + i] = cv;
}

extern "C" void kernel_launch(void* const* d_in, const int* in_sizes, int n_in,
                              void* d_out, int out_size, void* d_ws, size_t ws_size,
                              hipStream_t stream) {
    const float* x      = (const float*)d_in[0];   // [16, 2048]
    const float* params = (const float*)d_in[1];   // [16, 5]
    float* out          = (float*)d_out;           // 2 * 16 * 2048 floats

    const int grid = BATCH * (SIG_LEN / BLOCK);    // 128 blocks
    ParametricInterpolation_kernel<<<grid, BLOCK, 0, stream>>>(x, params, out);
}

// Round 2
// 54.441 us; speedup vs baseline: 1.0473x; 1.0473x over previous
//
#include <hip/hip_runtime.h>

#define SIG_LEN 2048
#define BATCH 16
#define BLOCK 256

// exp(-t^4) for integer t: only 5 distinct fp32 values, |t|>=4 underflows to 0.
#define W0 1.0f
#define W1 0.36787944117144233f   // exp(-1)
#define W2 1.1253517471925912e-07f // exp(-16)
#define W3 6.639677199580735e-36f  // exp(-81)

__global__ __launch_bounds__(BLOCK) void ParametricInterpolation_kernel(
    const float* __restrict__ x,       // [B, N]
    const float* __restrict__ params,  // [B, 5]
    float* __restrict__ out)           // [out | curve_val], each [B, N]
{
    __shared__ float xrow[SIG_LEN];

    const int b = blockIdx.x >> 3;                   // 8 blocks per batch row
    const int i = ((blockIdx.x & 7) << 8) + threadIdx.x;

    // Stage this batch-row of x into LDS: 2 coalesced float4 loads/thread.
    const float4* xb4 = (const float4*)(x + b * SIG_LEN);
    float4* xr4 = (float4*)xrow;
#pragma unroll
    for (int v = 0; v < (SIG_LEN / 4) / BLOCK; ++v)  // 2 iterations
        xr4[v * BLOCK + threadIdx.x] = xb4[v * BLOCK + threadIdx.x];
    __syncthreads();

    // p = params / SCALER, fp32 divides (correctly rounded, matches np).
    const float p0 = params[b * 5 + 0] / 1e11f;
    const float p1 = params[b * 5 + 1] / 1e7f;
    const float p2 = params[b * 5 + 2] / 1e3f;
    const float p3 = params[b * 5 + 3];
    const float p4 = params[b * 5 + 4];

    // powers of i: exact in double, rounded to fp32 (== np's correctly-rounded i**k).
    const double id = (double)i;
    const float pw4 = (float)(id * id * id * id);
    const float pw3 = (float)(id * id * id);
    const float pw2 = (float)(i * i);                // exact in fp32
    const float pw1 = (float)i;

    float cv = fmaf(p0, pw4, 0.0f);
    cv = fmaf(p1, pw3, cv);
    cv = fmaf(p2, pw2, cv);
    cv = fmaf(p3, pw1, cv);
    cv = cv + p4;

    const float ci = rintf(cv);          // round half-to-even == np.round
    const float d  = cv - ci;            // exact (Sterbenz)

    const float rawpos = (float)i - ci;  // exact integer in fp32
    const float npos   = fminf(fmaxf(rawpos, 1.0f), 2047.0f);
    const int   m      = (int)npos;      // in [1, 2047]

    // t = npos - j is an exact integer => weights are compile-time constants.
    // w1(dj) = T[dj+4], w2(dj) = T[dj+5]  (w2 center shifted by +1).
    const float T[10] = {0.0f, W3, W2, W1, W0, W1, W2, W3, 0.0f, 0.0f};

    float n1 = 0.0f, den1 = 0.0f, n2 = 0.0f, den2 = 0.0f;
#pragma unroll
    for (int dj = -4; dj <= 4; ++dj) {
        const int  j  = m + dj;
        const bool ok = (j >= 0) && (j < SIG_LEN);
        const int  jc = min(max(j, 0), SIG_LEN - 1);
        const float xv = xrow[jc];
        const float w1 = ok ? T[dj + 4] : 0.0f;   // folds to immediates
        const float w2 = ok ? T[dj + 5] : 0.0f;
        n1 = fmaf(xv, w1, n1);  den1 += w1;
        n2 = fmaf(xv, w2, n2);  den2 += w2;
    }

    const float a1 = n1 / den1;
    const float a2 = n2 / den2;
    const float o  = a1 * (1.0f - d) + a2 * d;

    out[b * SIG_LEN + i] = o;
    out[BATCH * SIG_LEN + b * SIG_LEN + i] = cv;
}

extern "C" void kernel_launch(void* const* d_in, const int* in_sizes, int n_in,
                              void* d_out, int out_size, void* d_ws, size_t ws_size,
                              hipStream_t stream) {
    const float* x      = (const float*)d_in[0];   // [16, 2048]
    const float* params = (const float*)d_in[1];   // [16, 5]
    float* out          = (float*)d_out;           // 2 * 16 * 2048 floats

    const int grid = BATCH * (SIG_LEN / BLOCK);    // 128 blocks
    ParametricInterpolation_kernel<<<grid, BLOCK, 0, stream>>>(x, params, out);
}